// Round 7
// baseline (270.307 us; speedup 1.0000x reference)
//
#include <hip/hip_runtime.h>
#include <stdint.h>

// B=131072 rows, K=IN=256, N=OUT=256.
// temp = act @ weight.T (exact int32, |t| < 2^22); r = max|temp|;
// bw = ceil(log2(max(r,1))) (0 if r<=1); shift = bw-7;
// shift>0 ? round_shift(temp,shift) clipped to [-127,127] : int8-wrap(temp)
// exp_out = exp_in + weight_exp + max(shift,0)  (int16 semantics)
// Harness reads d_out as INT32: [B*N values, 1 exp scalar].
//
// v8: v7 (int8 end-to-end, 267.6 us) + occupancy fix via split-N.
//  - v7 post-mortem: 104 KB LDS -> 1 block/CU -> 8 waves/CU (25% occ),
//    ~2.1-2.5 TB/s streaming. Work floor ~55 us; gap = latency hiding.
//  - k1: block = 128 rows x 128 cols (half N). LDS 34+34 KB -> 2 blocks/CU
//    -> 16 waves/CU. acc[4][2] = 32 regs/wave (<=128 cap, lb(512,4)).
//    Both col-halves read the same fp32 act (2nd hits LLC); only ch==0
//    converts+writes act8.
//  - k2: B-half in LDS (34 KB), A DIRECT global->reg from LLC-hot act8
//    (rows wave-private in recompute) -> no As LDS, barrier-free.

#define M_ROWS 131072
#define NK 256
#define TM 128            // rows per A-tile
#define TN 128            // cols per block (half N)
#define TILES 4           // A-tiles per block (512 rows/block-group)
#define LSTR 272          // LDS row stride bytes (256+16: rows walk 4 banks)

typedef __attribute__((ext_vector_type(4))) int iv4;
typedef __attribute__((ext_vector_type(4))) float fv4;
typedef __attribute__((ext_vector_type(4))) unsigned int u32x4;

// D = A*B + C, 16x16 K=64, signed i8 inputs, i32 accum (exact).
__device__ __forceinline__ iv4 mfma_i8(iv4 a, iv4 b, iv4 c) {
  asm("v_mfma_i32_16x16x64_i8 %0, %1, %2, %0" : "+v"(c) : "v"(a), "v"(b));
  return c;
}

// 4 int-valued floats -> 4 packed signed bytes (two's complement).
__device__ __forceinline__ unsigned int pack_i8x4(float a, float b, float c,
                                                  float d) {
  return ((unsigned int)(int)a & 0xFFu) | (((unsigned int)(int)b & 0xFFu) << 8) |
         (((unsigned int)(int)c & 0xFFu) << 16) | ((unsigned int)(int)d << 24);
}

// Prepass: weight fp32 -> i8 (65536 elems, 64 KB out; L2/LLC-resident).
// Also zero-inits gmax.
__global__ void wconv(const float* __restrict__ w, unsigned char* __restrict__ wi8,
                      int* __restrict__ gmax) {
  if (blockIdx.x == 0 && threadIdx.x == 0) *gmax = 0;
  const int i = blockIdx.x * 256 + threadIdx.x;
  const fv4 f = ((const fv4*)w)[i];
  ((unsigned int*)wi8)[i] = pack_i8x4(f.x, f.y, f.z, f.w);
}

// k1: act fp32 -> i8 (ch==0 stores act8) + i8 GEMM (half-N) -> global abs-max.
// 512 thr = 8 waves (2 row x 4 col); wave (wr,wc): rows wr*64..+63,
// cols wc*32..+31 of the 128x128 tile; acc iv4[4][2].
__global__ __launch_bounds__(512, 4) void gemm_max_cvt(
    const float* __restrict__ act, const unsigned char* __restrict__ wi8,
    unsigned char* __restrict__ act8, int* __restrict__ gmax)
{
  __shared__ __align__(16) unsigned char As[TM * LSTR];   // 34816 B
  __shared__ __align__(16) unsigned char Bs[TN * LSTR];   // 34816 B
  __shared__ int smax;
  const int tid = threadIdx.x;
  if (tid == 0) smax = 0;

  const int bx = blockIdx.x;
  const int ch = bx & 1;          // col half
  const int rg = bx >> 1;         // row group (TILES*TM rows)

  // Stage this block's B half (cols ch*128..+127).
  for (int c = tid; c < TN * NK / 16; c += 512) {
    const int col = c >> 4, kc = (c & 15) << 4;
    *(u32x4*)&Bs[col * LSTR + kc] =
        *(const u32x4*)(wi8 + (size_t)(ch * TN + col) * NK + kc);
  }

  const int lane = tid & 63;
  const int wave = tid >> 6;      // 0..7
  const int wr   = wave >> 2;     // 0..1
  const int wc   = wave & 3;      // 0..3
  const int lm   = lane & 15;
  const int lk   = lane >> 4;

  int imax = 0;

  for (int t = 0; t < TILES; ++t) {
    const int tb = rg * (TILES * TM) + t * TM;

    __syncthreads();   // protect As reuse (also covers Bs on t=0)
    // Stage A-tile fp32 -> i8; col-half 0 also writes act8 for k2.
#pragma unroll
    for (int j = 0; j < 4; ++j) {
      const int c   = j * 512 + tid;        // 2048 16B-chunks
      const int row = c >> 4;               // 0..127
      const int kc  = (c & 15) << 4;        // elem (=byte) offset
      const float* p = act + (size_t)(tb + row) * NK + kc;
      const fv4 f0 = ((const fv4*)p)[0];
      const fv4 f1 = ((const fv4*)p)[1];
      const fv4 f2 = ((const fv4*)p)[2];
      const fv4 f3 = ((const fv4*)p)[3];
      u32x4 v;
      v.x = pack_i8x4(f0.x, f0.y, f0.z, f0.w);
      v.y = pack_i8x4(f1.x, f1.y, f1.z, f1.w);
      v.z = pack_i8x4(f2.x, f2.y, f2.z, f2.w);
      v.w = pack_i8x4(f3.x, f3.y, f3.z, f3.w);
      *(u32x4*)&As[row * LSTR + kc] = v;
      if (ch == 0)
        *(u32x4*)(act8 + (size_t)(tb + row) * NK + kc) = v;   // -> LLC
    }
    __syncthreads();

    iv4 acc[4][2] = {};
#pragma unroll
    for (int kk = 0; kk < 4; ++kk) {        // K = 4 x 64
      iv4 af[4], bf[2];
#pragma unroll
      for (int mi = 0; mi < 4; ++mi)
        af[mi] = *(const iv4*)&As[(wr * 64 + mi * 16 + lm) * LSTR + kk * 64 + lk * 16];
#pragma unroll
      for (int ni = 0; ni < 2; ++ni)
        bf[ni] = *(const iv4*)&Bs[(wc * 32 + ni * 16 + lm) * LSTR + kk * 64 + lk * 16];
#pragma unroll
      for (int mi = 0; mi < 4; ++mi)
#pragma unroll
        for (int ni = 0; ni < 2; ++ni)
          acc[mi][ni] = mfma_i8(af[mi], bf[ni], acc[mi][ni]);
    }

#pragma unroll
    for (int mi = 0; mi < 4; ++mi)
#pragma unroll
      for (int ni = 0; ni < 2; ++ni)
#pragma unroll
        for (int r = 0; r < 4; ++r) {
          const int ti = acc[mi][ni][r];
          const int a = ti < 0 ? -ti : ti;
          imax = a > imax ? a : imax;
        }
  }

#pragma unroll
  for (int off = 32; off; off >>= 1) {
    const int o = __shfl_xor(imax, off, 64);
    imax = o > imax ? o : imax;
  }
  if (lane == 0) atomicMax(&smax, imax);
  __syncthreads();
  if (tid == 0) atomicMax(gmax, smax);
}

// k2: i8 GEMM recompute (half-N); A direct global->reg (act8 LLC-hot, rows
// wave-private), B-half in LDS. Quantize in regs -> final nt-store.
__global__ __launch_bounds__(512, 4) void gemm_quant(
    const unsigned char* __restrict__ act8, const unsigned char* __restrict__ wi8,
    int* __restrict__ out, const int* __restrict__ gmax,
    const int* __restrict__ exp_in, const int* __restrict__ wexp)
{
  __shared__ __align__(16) unsigned char Bs[TN * LSTR];   // 34816 B

  const int rmax = *gmax;
  const int bw = (rmax <= 1) ? 0 : (32 - __clz(rmax - 1));   // ceil(log2(r))
  const int shift = bw - 7;
  const bool pos = shift > 0;
  const int s = shift < 1 ? 1 : shift;

  const int tid = threadIdx.x;
  const int bx = blockIdx.x;
  const int ch = bx & 1;
  const int rg = bx >> 1;

  for (int c = tid; c < TN * NK / 16; c += 512) {
    const int col = c >> 4, kc = (c & 15) << 4;
    *(u32x4*)&Bs[col * LSTR + kc] =
        *(const u32x4*)(wi8 + (size_t)(ch * TN + col) * NK + kc);
  }
  __syncthreads();   // only barrier

  const int lane = tid & 63;
  const int wave = tid >> 6;
  const int wr   = wave >> 2;
  const int wc   = wave & 3;
  const int lm   = lane & 15;
  const int lk   = lane >> 4;

  for (int t = 0; t < TILES; ++t) {
    const int tb = rg * (TILES * TM) + t * TM;
    const unsigned char* arow =
        act8 + (size_t)(tb + wr * 64 + lm) * NK + lk * 16;

    iv4 acc[4][2] = {};
#pragma unroll
    for (int kk = 0; kk < 4; ++kk) {
      iv4 af[4], bf[2];
#pragma unroll
      for (int mi = 0; mi < 4; ++mi)
        af[mi] = *(const iv4*)(arow + (size_t)(mi * 16) * NK + kk * 64);
#pragma unroll
      for (int ni = 0; ni < 2; ++ni)
        bf[ni] = *(const iv4*)&Bs[(wc * 32 + ni * 16 + lm) * LSTR + kk * 64 + lk * 16];
#pragma unroll
      for (int mi = 0; mi < 4; ++mi)
#pragma unroll
        for (int ni = 0; ni < 2; ++ni)
          acc[mi][ni] = mfma_i8(af[mi], bf[ni], acc[mi][ni]);
    }

    // Quantize + final nt-store.
#pragma unroll
    for (int mi = 0; mi < 4; ++mi)
#pragma unroll
      for (int ni = 0; ni < 2; ++ni)
#pragma unroll
        for (int r = 0; r < 4; ++r) {
          const int ti = acc[mi][ni][r];
          int q;
          if (pos) {
            const int rt = ti >> s;                       // floor(t / 2^s)
            const int dec = (ti - (rt << s)) >> (s - 1);  // {0,1}
            q = rt + dec;
            q = q > 127 ? 127 : (q < -127 ? -127 : q);
          } else {
            q = (int)(signed char)(ti & 0xFF);            // int8 wrap
          }
          const int m = tb + wr * 64 + mi * 16 + lk * 4 + r;
          const int n = ch * TN + wc * 32 + ni * 16 + lm;
          __builtin_nontemporal_store(q, &out[(size_t)m * NK + n]);
        }
  }

  if (bx == 0 && tid == 0) {
    const int e = exp_in[0] + wexp[0] + (pos ? shift : 0);
    out[(size_t)M_ROWS * NK] = (int)(short)e;
  }
}

extern "C" void kernel_launch(void* const* d_in, const int* in_sizes, int n_in,
                              void* d_out, int out_size, void* d_ws, size_t ws_size,
                              hipStream_t stream) {
  const float* act   = (const float*)d_in[0];
  const int* exp_in  = (const int*)d_in[1];
  const float* wgt   = (const float*)d_in[2];
  const int* wexp    = (const int*)d_in[3];
  int* gmax           = (int*)d_ws;
  unsigned char* wi8  = (unsigned char*)d_ws + 4096;        // 64 KB
  unsigned char* act8 = (unsigned char*)d_ws + (1 << 20);   // 33.5 MB

  const int nblk = (M_ROWS / (TILES * TM)) * 2;   // 512: 2 blocks/CU exactly
  wconv<<<dim3(64), dim3(256), 0, stream>>>(wgt, wi8, gmax);
  gemm_max_cvt<<<dim3(nblk), dim3(512), 0, stream>>>(act, wi8, act8, gmax);
  gemm_quant<<<dim3(nblk), dim3(512), 0, stream>>>(act8, wi8, (int*)d_out,
                                                   gmax, exp_in, wexp);
}